// Round 17
// baseline (4518.056 us; speedup 1.0000x reference)
//
#include <hip/hip_runtime.h>
#include <hip/hip_cooperative_groups.h>

namespace cg = cooperative_groups;

#define NB 4
#define NN 256
#define ND 128

// LDS layout (floats/uints, 4B units):
//  Wl    [16384]  W staged fp32 (64KB)
//  Xlu   [16640]  batch X staged as bf16x2 words, stride 65/row (padded)
//  Al    [1024]   own 4 rows of A (fp32)
//  prob  [256]
//  dinv  [256]
//  arow  [256]
//  srow  [1024]
//  ypart [2048]
//  yrow  [512]
//  red   [8]
#define LDS_FLOATS 38408   // 153,632 B

__device__ __forceinline__ float2 ld2(const float* p) {
    return *reinterpret_cast<const float2*>(p);
}

// ---- coherence-point (agent-scope relaxed atomic) access ----
__device__ __forceinline__ unsigned long long ldcu8(const unsigned long long* p) {
    return __hip_atomic_load(p, __ATOMIC_RELAXED, __HIP_MEMORY_SCOPE_AGENT);
}
__device__ __forceinline__ float ldc(const float* p) {
    unsigned u = __hip_atomic_load((const unsigned*)p,
                    __ATOMIC_RELAXED, __HIP_MEMORY_SCOPE_AGENT);
    return __uint_as_float(u);
}
__device__ __forceinline__ void stc(float* p, float v) {
    __hip_atomic_store((unsigned*)p, __float_as_uint(v),
                       __ATOMIC_RELAXED, __HIP_MEMORY_SCOPE_AGENT);
}
__device__ __forceinline__ void stcu(unsigned* p, unsigned v) {
    __hip_atomic_store(p, v, __ATOMIC_RELAXED, __HIP_MEMORY_SCOPE_AGENT);
}

// bf16 helpers (RNE pack, cheap unpack)
__device__ __forceinline__ unsigned f2bf(float f) {
    unsigned u = __float_as_uint(f);
    return (u + 0x7fffu + ((u >> 16) & 1u)) >> 16;
}
__device__ __forceinline__ float bflo(unsigned w) { return __uint_as_float(w << 16); }
__device__ __forceinline__ float bfhi(unsigned w) { return __uint_as_float(w & 0xffff0000u); }
__device__ __forceinline__ unsigned packbf(float a, float b) {
    return f2bf(a) | (f2bf(b) << 16);
}

// Fence-free per-batch barrier (proven round 15): data path is all
// coherence-point atomics; __syncthreads' vmcnt(0) drain orders stores
// before the flag store. Monotonic step values -> no reset, no ABA.
__device__ __forceinline__ void batch_barrier(int* flg, int step, int w) {
    __syncthreads();
    if (threadIdx.x == 0)
        __hip_atomic_store(flg + w, step, __ATOMIC_RELAXED, __HIP_MEMORY_SCOPE_AGENT);
    if (threadIdx.x < 64) {
        while (__hip_atomic_load(flg + threadIdx.x, __ATOMIC_RELAXED,
                                 __HIP_MEMORY_SCOPE_AGENT) < step)
            __builtin_amdgcn_s_sleep(1);
    }
    asm volatile("" ::: "memory");
    __syncthreads();
}

extern "C" __global__ void __launch_bounds__(256, 1)
gcn_coop_kernel(const float* __restrict__ Xin, const float* __restrict__ Wg,
                float* __restrict__ out, float* __restrict__ ws)
{
    extern __shared__ float lds[];
    float*    Wl    = lds;                         // 16384
    unsigned* Xlu   = (unsigned*)(lds + 16384);    // 16640 (stride 65 words/row)
    float*    Al    = lds + 33024;                 // 1024
    float*    prob  = lds + 34048;                 // 256
    float*    dinv  = lds + 34304;                 // 256
    float*    arow  = lds + 34560;                 // 256
    float*    srow  = lds + 34816;                 // 1024
    float*    ypart = lds + 35840;                 // 2048
    float*    yrow  = lds + 37888;                 // 512
    float*    red   = lds + 38400;                 // 8

    const int tid  = threadIdx.x;
    const int lane = tid & 63;
    const int v    = tid >> 6;                 // wave id 0..3
    // XCD-confined mapping: batch b -> XCDs {2b, 2b+1}
    const int b    = (blockIdx.x & 7) >> 1;    // batch 0..3
    const int w    = (blockIdx.x & 1) * 32 + (blockIdx.x >> 3);  // 0..63
    const int n0   = w << 2;                   // first owned row
    const int nv   = n0 + v;                   // this wave's row

    // ws layout: X bf16 ping-pong (NB*NN*64 uints each), then R/AR fp32, then flags
    unsigned* XU0 = (unsigned*)ws;
    unsigned* XU1 = XU0 + NB*NN*64;
    float*    R0  = (float*)(XU1 + NB*NN*64);
    float*    R1  = R0 + NB*NN;
    float*    AR0 = R1 + NB*NN;
    float*    AR1 = AR0 + NB*NN;
    int*      flg = (int*)(AR1 + NB*NN);       // flg[b*64 + w], monotonic steps

    // ---- stage W into LDS (once) ----
    {
        const float4* Wg4 = reinterpret_cast<const float4*>(Wg);
        float4* Wl4 = reinterpret_cast<float4*>(Wl);
        #pragma unroll
        for (int k = 0; k < 16; ++k) Wl4[tid + 256*k] = Wg4[tid + 256*k];
    }
    // stage own Xin row into yrow
    {
        const float2* src = reinterpret_cast<const float2*>(Xin + (b*NN + nv)*ND);
        reinterpret_cast<float2*>(yrow + v*ND)[lane] = src[lane];
    }
    if (tid == 0)
        __hip_atomic_store(flg + b*64 + w, 0, __ATOMIC_RELAXED, __HIP_MEMORY_SCOPE_AGENT);
    __syncthreads();

    // ---- init: x0 = relu(Xin @ W) -> bf16 X0; Al = I-rows; rs0 = 1; AR0 = e_1; out diag
    {
        float a0 = 0.f, a1 = 0.f;
        const float4* yr4 = reinterpret_cast<const float4*>(yrow + v*ND);
        #pragma unroll 4
        for (int dd = 0; dd < 32; ++dd) {
            float4 y4 = yr4[dd];
            float2 w0 = ld2(Wl + (4*dd+0)*ND + 2*lane);
            float2 w1 = ld2(Wl + (4*dd+1)*ND + 2*lane);
            float2 w2 = ld2(Wl + (4*dd+2)*ND + 2*lane);
            float2 w3 = ld2(Wl + (4*dd+3)*ND + 2*lane);
            a0 += y4.x*w0.x; a1 += y4.x*w0.y;
            a0 += y4.y*w1.x; a1 += y4.y*w1.y;
            a0 += y4.z*w2.x; a1 += y4.z*w2.y;
            a0 += y4.w*w3.x; a1 += y4.w*w3.y;
        }
        stcu(XU0 + (b*NN+nv)*64 + lane, packbf(fmaxf(a0,0.f), fmaxf(a1,0.f)));
        #pragma unroll
        for (int rr = 0; rr < 4; ++rr)
            Al[rr*NN + tid] = (tid == n0 + rr) ? 1.f : 0.f;
        if (lane == 0) {
            stc(R0 + b*NN + nv, 1.f);
            out[(b*NN+nv)*NN + nv] = 1.f;
        }
        if (w == 0) stc(AR0 + b*NN + tid, (tid == 1) ? 1.f : 0.f);
    }

    cg::grid_group grid = cg::this_grid();

    for (int i = 1; i < NN; ++i) {
        if (i == 1) grid.sync();                  // publishes init data AND zeroed flags
        else        batch_barrier(flg + b*64, i, w);
        const int cur = (i-1) & 1;
        const unsigned* Xcu = cur ? XU1 : XU0;
        unsigned*       Xnu = cur ? XU0 : XU1;
        const float* Rc  = cur ? R1 : R0;
        float*       Rn  = cur ? R0 : R1;
        const float* ARc = cur ? AR1 : AR0;
        float*       ARn = cur ? AR0 : AR1;

        // ---- stage whole batch X (bf16) into LDS: 8192 x 8B coherent loads ----
        {
            const unsigned long long* src =
                reinterpret_cast<const unsigned long long*>(Xcu + b*NN*64);
            #pragma unroll
            for (int k = 0; k < 32; ++k) {
                const int q   = tid + (k << 8);      // 0..8191 (32 ull per row)
                unsigned long long d = ldcu8(src + q);
                const int row = q >> 5;
                const int c2  = (q & 31) << 1;
                Xlu[row*65 + c2]     = (unsigned)d;
                Xlu[row*65 + c2 + 1] = (unsigned)(d >> 32);
            }
        }
        arow[tid] = ldc(ARc + b*NN + tid);
        __syncthreads();

        // prob[t] = x[t]·x[i]  (t < i), from LDS bf16; deg partials for row i
        float pv = 0.f;
        if (tid < i) {
            const unsigned* xr = Xlu + tid*65;
            const unsigned* xc = Xlu + i*65;
            float p0 = 0.f, p1 = 0.f;
            #pragma unroll 16
            for (int k = 0; k < 64; ++k) {
                const unsigned a = xr[k];
                const unsigned c = xc[k];      // broadcast
                p0 += bflo(a) * bflo(c);
                p1 += bfhi(a) * bfhi(c);
            }
            pv = p0 + p1;
        }
        float pd = (tid < i) ? (pv - arow[tid]) : 0.f;
        #pragma unroll
        for (int off = 32; off; off >>= 1) pd += __shfl_down(pd, off, 64);
        if (lane == 0) red[v] = pd;
        prob[tid] = pv;
        __syncthreads();

        // deg -> dinv (redundant in every block)
        {
            const float rc = ldc(Rc + b*NN + tid);
            float deg;
            if (tid < i)      deg = rc - arow[tid] + pv;
            else if (tid > i) deg = rc;
            else              deg = rc + red[0] + red[1] + red[2] + red[3];
            dinv[tid] = rsqrtf(deg);
        }
        __syncthreads();

        // ---- loop A: s[j] = M[n,j]*dinv[j]; update Al in place; adj_out row/col i
        {
            const int j = tid;
            const float dj = dinv[j];
            float sv[4];
            #pragma unroll
            for (int r = 0; r < 4; ++r) {
                const int n = n0 + r;
                float m;
                if (n == i)      m = (j < i) ? prob[j] : Al[r*NN + j];
                else if (j == i) m = (n < i) ? prob[n] : Al[r*NN + j];
                else             m = Al[r*NN + j];
                const float s = m * dj;
                sv[r] = s;
                Al[r*NN + j] = dinv[n] * s;
                if (n == i && j < i) out[(b*NN+i)*NN + j] = prob[j];
            }
            if (j == i) {
                #pragma unroll
                for (int r = 0; r < 4; ++r) {
                    const int n = n0 + r;
                    if (n < i) out[(b*NN+n)*NN + i] = prob[n];
                }
            }
            reinterpret_cast<float4*>(srow)[j] = make_float4(sv[0], sv[1], sv[2], sv[3]);
        }
        __syncthreads();

        if (i < NN-1) {
            // publish next pivot row A_next[i+1,:] (owner block only)
            {
                const unsigned rr = (unsigned)(i + 1 - n0);
                if (rr < 4u) stc(ARn + b*NN + tid, Al[rr*NN + tid]);
            }
            // rs_next for own row
            {
                float sacc = srow[lane*4 + v] + srow[(lane+64)*4 + v]
                           + srow[(lane+128)*4 + v] + srow[(lane+192)*4 + v];
                #pragma unroll
                for (int off = 32; off; off >>= 1) sacc += __shfl_down(sacc, off, 64);
                if (lane == 0) stc(Rn + b*NN + nv, dinv[nv] * sacc);
            }
            // ---- loop B: y partials from LDS bf16 X; wave v covers j in [64v,64v+64)
            float y0x=0,y0y=0,y1x=0,y1y=0,y2x=0,y2y=0,y3x=0,y3y=0;
            const float4* srow4 = reinterpret_cast<const float4*>(srow);
            #pragma unroll 8
            for (int jj = 0; jj < 64; ++jj) {
                const int jB = v*64 + jj;
                const float4 s  = srow4[jB];           // LDS broadcast
                const unsigned xw = Xlu[jB*65 + lane]; // 2-way max
                const float xvx = bflo(xw), xvy = bfhi(xw);
                y0x += s.x*xvx; y0y += s.x*xvy;
                y1x += s.y*xvx; y1y += s.y*xvy;
                y2x += s.z*xvx; y2y += s.z*xvy;
                y3x += s.w*xvx; y3y += s.w*xvy;
            }
            float2* yp2 = reinterpret_cast<float2*>(ypart);
            yp2[(v*4+0)*64 + lane] = make_float2(y0x,y0y);
            yp2[(v*4+1)*64 + lane] = make_float2(y1x,y1y);
            yp2[(v*4+2)*64 + lane] = make_float2(y2x,y2y);
            yp2[(v*4+3)*64 + lane] = make_float2(y3x,y3y);
            __syncthreads();
            // reduce partials for own row, apply dinv[n]
            {
                float2 a  = yp2[(0*4+v)*64 + lane];
                float2 t1 = yp2[(1*4+v)*64 + lane];
                float2 t2 = yp2[(2*4+v)*64 + lane];
                float2 t3 = yp2[(3*4+v)*64 + lane];
                a.x += t1.x + t2.x + t3.x;
                a.y += t1.y + t2.y + t3.y;
                const float dn = dinv[nv];
                a.x *= dn; a.y *= dn;
                reinterpret_cast<float2*>(yrow + v*ND)[lane] = a;
            }
            // ---- loop C: x_next = relu(y @ W), store bf16 ----
            {
                float a0 = 0.f, a1 = 0.f;
                const float4* yr4 = reinterpret_cast<const float4*>(yrow + v*ND);
                #pragma unroll 4
                for (int dd = 0; dd < 32; ++dd) {
                    float4 y4 = yr4[dd];
                    float2 w0 = ld2(Wl + (4*dd+0)*ND + 2*lane);
                    float2 w1 = ld2(Wl + (4*dd+1)*ND + 2*lane);
                    float2 w2 = ld2(Wl + (4*dd+2)*ND + 2*lane);
                    float2 w3 = ld2(Wl + (4*dd+3)*ND + 2*lane);
                    a0 += y4.x*w0.x; a1 += y4.x*w0.y;
                    a0 += y4.y*w1.x; a1 += y4.y*w1.y;
                    a0 += y4.z*w2.x; a1 += y4.z*w2.y;
                    a0 += y4.w*w3.x; a1 += y4.w*w3.y;
                }
                stcu(Xnu + (b*NN+nv)*64 + lane, packbf(fmaxf(a0,0.f), fmaxf(a1,0.f)));
            }
        }
    }
}

extern "C" void kernel_launch(void* const* d_in, const int* in_sizes, int n_in,
                              void* d_out, int out_size, void* d_ws, size_t ws_size,
                              hipStream_t stream)
{
    const float* x  = (const float*)d_in[0];
    const float* W  = (const float*)d_in[1];
    float* out      = (float*)d_out;
    float* ws       = (float*)d_ws;
    (void)in_sizes; (void)n_in; (void)out_size; (void)ws_size;

    hipFuncSetAttribute(reinterpret_cast<const void*>(gcn_coop_kernel),
                        hipFuncAttributeMaxDynamicSharedMemorySize,
                        LDS_FLOATS * 4);

    void* args[] = { (void*)&x, (void*)&W, (void*)&out, (void*)&ws };
    hipLaunchCooperativeKernel(reinterpret_cast<void*>(gcn_coop_kernel),
                               dim3(NB*64), dim3(256),
                               args, LDS_FLOATS * 4, stream);
}